// Round 19
// baseline (25216.017 us; speedup 1.0000x reference)
//
#include <hip/hip_runtime.h>
#include <math.h>

#define L_SEQ 8192
#define I_DIM 256
#define H_DIM 2048
#define NWG   128         // merged: each WG owns 16 h0-rows AND 16 h1-rows
#define TPB   512
#define RD    16          // ring depth
#define RM    (RD - 1)
#define NSTEP (L_SEQ + 1) // s=1..8193; step s computes h0_s (s<=8192) and h1_{s-1} (s>=2)

// ws (bytes): [0] runctr | [256..768) bslots[128] | [4096) h0 ring 16*2048 f32
//             | [135168) h1 ring 16*2048 f32
//
// MERGED-LAYER dataflow (round 19). Single WG set; the only FRESH cross-WG
// dependency per step is h0_{s-1}. Step s: detect h0_{s-1} (poll), stage; also
// stage h1_{s-2} from a prefetch issued last step (2-step-old data). One sync.
// Critical: L0 dot (2 rows x 8 f4) + publish h0_s. Hidden phase (overlaps next
// step's visibility window): L1 ih+hh dots (bf16-packed weights), publish
// h1_{s-1}, x-partials for s+1, issue h1_{s-1} prefetch. No throttle needed:
// all WGs validate full h0_{s-1} each step => peers within 1 step => ring-16
// has margin ~14 for both rings.
// Protocol (proven r12-r17): value = h + ctr(step), ctr = 4+8*((step>>4)&1),
// valid iff |v-ctr|<=1; per-run slot re-init (slot0 = tagged h_0 = 4.0, rest
// 0.0 invalid); 0xAA poison and 0.0 fail both tag windows; start barrier on
// monotone runctr. Weights constant-unrolled (no-scratch codegen): Whh0+Wih0
// fp32 f4 arrays (L0 exact), Wih1+Whh1 bf16-packed dwords (64 regs saved;
// accuracy bounded by r9's q15 precedent: 1.2e-4 h-quant -> absmax 0).

typedef float f32x4 __attribute__((ext_vector_type(4)));
typedef float f32x2 __attribute__((ext_vector_type(2)));

__device__ __forceinline__ void cstore1(float* p, float v) {
  asm volatile("global_store_dword %0, %1, off sc0 sc1" :: "v"(p), "v"(v) : "memory");
}
__device__ __forceinline__ void cstore2f(float* p, float a, float b) {
  f32x2 v; v.x = a; v.y = b;
  asm volatile("global_store_dwordx2 %0, %1, off sc0 sc1" :: "v"(p), "v"(v) : "memory");
}
__device__ __forceinline__ void cstoreu(unsigned* p, unsigned v) {
  asm volatile("global_store_dword %0, %1, off sc0 sc1" :: "v"(p), "v"(v) : "memory");
}
__device__ __forceinline__ unsigned cloadu(const unsigned* p) {
  unsigned v;
  asm volatile("global_load_dword %0, %1, off sc0 sc1\n\ts_waitcnt vmcnt(0)"
               : "=v"(v) : "v"(p) : "memory");
  return v;
}
__device__ __forceinline__ float4 cload4(const float* p) {
  float4 v;
  asm volatile("global_load_dwordx4 %0, %1, off sc0 sc1\n\ts_waitcnt vmcnt(0)"
               : "=v"(v) : "v"(p) : "memory");
  return v;
}
__device__ __forceinline__ float4 ld4(const float* p) {   // weight load, opaque
  float4 v;
  asm volatile("global_load_dwordx4 %0, %1, off\n\ts_waitcnt vmcnt(0)"
               : "=v"(v) : "v"(p) : "memory");
  return v;
}
// prefetch: issue WITHOUT waitcnt; drained by later vmcnt(0)s (poll4 内)
__device__ __forceinline__ void pf_issue(f32x4& v, const float* p) {
  asm volatile("global_load_dwordx4 %0, %1, off sc0 sc1" : "=&v"(v) : "v"(p) : "memory");
}
__device__ __forceinline__ void pf_wait0(f32x4& v) {   // uniform full drain
  asm volatile("s_waitcnt vmcnt(0)" : "+v"(v) :: "memory");
  __builtin_amdgcn_sched_barrier(0);
}
__device__ __forceinline__ float tagc(int step) {
  return 4.f + 8.f * (float)((step >> 4) & 1);
}
__device__ __forceinline__ bool ok4(float4 v, float c) {
  return __builtin_fabsf(v.x - c) <= 1.f && __builtin_fabsf(v.y - c) <= 1.f &&
         __builtin_fabsf(v.z - c) <= 1.f && __builtin_fabsf(v.w - c) <= 1.f;
}
__device__ __forceinline__ bool ok4x(f32x4 v, float c) {
  return __builtin_fabsf(v.x - c) <= 1.f && __builtin_fabsf(v.y - c) <= 1.f &&
         __builtin_fabsf(v.z - c) <= 1.f && __builtin_fabsf(v.w - c) <= 1.f;
}
__device__ __forceinline__ float4 poll4(const float* p, float c) {
  float4 v = cload4(p);
  while (!ok4(v, c)) { __builtin_amdgcn_s_sleep(1); v = cload4(p); }
  return make_float4(v.x - c, v.y - c, v.z - c, v.w - c);
}
__device__ __forceinline__ float4 pf_finish(f32x4 pf, const float* p, float c) {
  if (!ok4x(pf, c)) {
    do {
      __builtin_amdgcn_s_sleep(1);
      float4 r = cload4(p);
      pf.x = r.x; pf.y = r.y; pf.z = r.z; pf.w = r.w;
    } while (!ok4x(pf, c));
  }
  return make_float4(pf.x - c, pf.y - c, pf.z - c, pf.w - c);
}
__device__ __forceinline__ float dot4(float4 a, float4 b) {
  return a.x * b.x + a.y * b.y + a.z * b.z + a.w * b.w;
}
__device__ __forceinline__ float tanh_fast(float v) {   // exact identity
  float e = __expf(2.f * v);
  return 1.f - 2.f / (e + 1.f);
}
// bf16 pack (round-to-nearest-even) / unpack
__device__ __forceinline__ unsigned bfp(float a, float b) {
  unsigned ua = __float_as_uint(a), ub = __float_as_uint(b);
  ua += 0x7fffu + ((ua >> 16) & 1u);
  ub += 0x7fffu + ((ub >> 16) & 1u);
  return (ua >> 16) | (ub & 0xffff0000u);
}
__device__ __forceinline__ float blo(unsigned w) { return __uint_as_float(w << 16); }
__device__ __forceinline__ float bhi(unsigned w) { return __uint_as_float(w & 0xffff0000u); }

__device__ __forceinline__ void start_barrier(unsigned* bslots, int wg, int tid, unsigned value) {
  __syncthreads();
  if (tid == 0) cstoreu(&bslots[wg], value);
  if (tid < NWG) {
    while ((int)(cloadu(&bslots[tid]) - value) < 0) __builtin_amdgcn_s_sleep(1);
  }
  __syncthreads();
}

__global__ __launch_bounds__(TPB, 2)
void rnn2_merged(const float* __restrict__ x,
                 const float* __restrict__ Wih0, const float* __restrict__ Whh0,
                 const float* __restrict__ bih0, const float* __restrict__ bhh0,
                 const float* __restrict__ Wih1, const float* __restrict__ Whh1,
                 const float* __restrict__ bih1, const float* __restrict__ bhh1,
                 const float* __restrict__ Wfc,  const float* __restrict__ bfc,
                 float* __restrict__ out,
                 unsigned* __restrict__ runctr, unsigned* __restrict__ bslots,
                 float* __restrict__ h0s, float* __restrict__ h1s)
{
  const int wg   = blockIdx.x;
  const int tid  = threadIdx.x;
  const int lane = tid & 63;
  const int wv   = tid >> 6;
  __shared__ float4 lds4[2][1152];   // [0..576) h0_{s-1} padded, [576..1152) h1_{s-2}

  const unsigned runbase = cloadu(runctr);

  // wave wv owns h0 rows {r0, r0+1} and h1 rows {r0, r0+1}; lane owns 32 cols
  const int r0 = wg * 16 + wv * 2;

  // ---- L0 weights (fp32): Whh0 2 rows x 8 f4; Wih0 2 rows x 1 f4 ----
  float4 whh0r[16];   // [j*8+k]
  float4 wih0r[2];
  {
    #pragma unroll
    for (int j = 0; j < 2; ++j) {
      const float* wr = Whh0 + (size_t)(r0 + j) * H_DIM + (lane << 5);
      #pragma unroll
      for (int k = 0; k < 8; ++k) whh0r[j * 8 + k] = ld4(wr + (k << 2));
      wih0r[j] = ld4(Wih0 + (size_t)(r0 + j) * I_DIM + (lane << 2));
    }
  }
  // ---- L1 weights (bf16-packed): Wih1/Whh1, 2 rows x 16 dwords each ----
  unsigned wih1q[32], whh1q[32];   // [j*16 + d]
  {
    #pragma unroll
    for (int j = 0; j < 2; ++j) {
      const float* wr = Wih1 + (size_t)(r0 + j) * H_DIM + (lane << 5);
      #pragma unroll
      for (int k = 0; k < 8; ++k) {
        float4 v = ld4(wr + (k << 2));
        wih1q[j * 16 + 2 * k]     = bfp(v.x, v.y);
        wih1q[j * 16 + 2 * k + 1] = bfp(v.z, v.w);
      }
      const float* wr2 = Whh1 + (size_t)(r0 + j) * H_DIM + (lane << 5);
      #pragma unroll
      for (int k = 0; k < 8; ++k) {
        float4 v = ld4(wr2 + (k << 2));
        whh1q[j * 16 + 2 * k]     = bfp(v.x, v.y);
        whh1q[j * 16 + 2 * k + 1] = bfp(v.z, v.w);
      }
    }
  }
  const float b00 = bih0[r0] + bhh0[r0];
  const float b01 = bih0[r0 + 1] + bhh0[r0 + 1];
  const float b10 = bih1[r0] + bhh1[r0];
  const float b11 = bih1[r0 + 1] + bhh1[r0 + 1];

  if (tid < 256) {   // re-init all 16 ring slots of owned rows, both rings
    int sl = tid >> 4; int r = wg * 16 + (tid & 15);
    float v = (sl == 0) ? 4.f : 0.f;
    cstore1(&h0s[sl * H_DIM + r], v);
    cstore1(&h1s[sl * H_DIM + r], v);
  }
  start_barrier(bslots, wg, tid, runbase + 1);

  // x-partials for s=1 (x_1 = x[0])
  float xp0, xp1;
  {
    float4 xv = ((const float4*)x)[lane];
    xp0 = dot4(wih0r[0], xv); xp1 = dot4(wih0r[1], xv);
  }
  f32x4 pfA; pfA.x = 0.f; pfA.y = 0.f; pfA.z = 0.f; pfA.w = 0.f;

  for (int s = 1; s <= NSTEP; ++s) {
    const int P = s & 1;
    // ---- staging: h1_{s-2} from prefetch (old data), h0_{s-1} fresh poll ----
    if (s >= 2) {
      const float c1 = tagc(s - 2);
      pf_wait0(pfA);
      lds4[P][576 + tid + (tid >> 3)] =
          pf_finish(pfA, h1s + ((s - 2) & RM) * H_DIM + (tid << 2), c1);
    }
    {
      const float c0 = tagc(s - 1);
      lds4[P][tid + (tid >> 3)] =
          poll4(h0s + ((s - 1) & RM) * H_DIM + (tid << 2), c0);
    }
    __syncthreads();

    // ---- critical: L0 dot + publish h0_s ----
    if (s <= L_SEQ) {
      float p0 = xp0, p1 = xp1;
      #pragma unroll
      for (int k = 0; k < 8; ++k) {
        float4 h = lds4[P][9 * lane + k];
        p0 += dot4(whh0r[k], h);
        p1 += dot4(whh0r[8 + k], h);
      }
      #pragma unroll
      for (int m = 1; m < 64; m <<= 1) {
        p0 += __shfl_xor(p0, m); p1 += __shfl_xor(p1, m);
      }
      if (lane == 0) {
        const float ct = tagc(s);
        cstore2f(h0s + (s & RM) * H_DIM + r0,
                 tanh_fast(p0 + b00) + ct, tanh_fast(p1 + b01) + ct);
      }
    }

    // ---- hidden phase: L1 compute + publish, x-partials, h1 prefetch ----
    if (s >= 2) {
      float qa = 0.f, qb = 0.f;
      #pragma unroll
      for (int k = 0; k < 8; ++k) {      // ih over staged h0_{s-1}
        float4 h = lds4[P][9 * lane + k];
        unsigned wa0 = wih1q[2 * k], wa1 = wih1q[2 * k + 1];
        unsigned wb0 = wih1q[16 + 2 * k], wb1 = wih1q[16 + 2 * k + 1];
        qa += blo(wa0) * h.x + bhi(wa0) * h.y + blo(wa1) * h.z + bhi(wa1) * h.w;
        qb += blo(wb0) * h.x + bhi(wb0) * h.y + blo(wb1) * h.z + bhi(wb1) * h.w;
      }
      #pragma unroll
      for (int k = 0; k < 8; ++k) {      // hh over staged h1_{s-2}
        float4 h = lds4[P][576 + 9 * lane + k];
        unsigned wa0 = whh1q[2 * k], wa1 = whh1q[2 * k + 1];
        unsigned wb0 = whh1q[16 + 2 * k], wb1 = whh1q[16 + 2 * k + 1];
        qa += blo(wa0) * h.x + bhi(wa0) * h.y + blo(wa1) * h.z + bhi(wa1) * h.w;
        qb += blo(wb0) * h.x + bhi(wb0) * h.y + blo(wb1) * h.z + bhi(wb1) * h.w;
      }
      #pragma unroll
      for (int m = 1; m < 64; m <<= 1) {
        qa += __shfl_xor(qa, m); qb += __shfl_xor(qb, m);
      }
      if (lane == 0) {
        const float ct = tagc(s - 1);
        cstore2f(h1s + ((s - 1) & RM) * H_DIM + r0,
                 tanh_fast(qa + b10) + ct, tanh_fast(qb + b11) + ct);
      }
    }
    if (s < L_SEQ) {   // x-partials for step s+1 (x_{s+1} = x[s])
      float4 xv = ((const float4*)x)[s * 64 + lane];
      xp0 = dot4(wih0r[0], xv); xp1 = dot4(wih0r[1], xv);
    }
    if (s < NSTEP) {   // prefetch h1_{s-1} for next iter (issued as late as possible)
      pf_issue(pfA, h1s + ((s - 1) & RM) * H_DIM + (tid << 2));
    }
  }

  if (wg == 0) {
    // FC: sigmoid(h1_8192 . Wfc + bfc); slot 8192&15 = 0, ctr 4.
    // Slot 0's previous occupant h1_8176 has ctr 12 (rejected).
    float4 hv = poll4(h1s + (tid << 2), tagc(L_SEQ));
    float4 wf = ((const float4*)Wfc)[tid];
    float pz = dot4(hv, wf);
    #pragma unroll
    for (int m = 1; m < 64; m <<= 1) pz += __shfl_xor(pz, m);
    float* red = (float*)&lds4[0][0];
    __syncthreads();
    if ((tid & 63) == 0) red[wv] = pz;
    __syncthreads();
    if (tid == 0) {
      float z = bfc[0];
      #pragma unroll
      for (int w = 0; w < 8; ++w) z += red[w];
      out[0] = 1.f / (1.f + __expf(-z));
      cstoreu(runctr, runbase + 1);
    }
  }
}

extern "C" void kernel_launch(void* const* d_in, const int* in_sizes, int n_in,
                              void* d_out, int out_size, void* d_ws, size_t ws_size,
                              hipStream_t stream) {
  const float* xx   = (const float*)d_in[0];
  const float* Wih0 = (const float*)d_in[1];
  const float* Whh0 = (const float*)d_in[2];
  const float* bih0 = (const float*)d_in[3];
  const float* bhh0 = (const float*)d_in[4];
  const float* Wih1 = (const float*)d_in[5];
  const float* Whh1 = (const float*)d_in[6];
  const float* bih1 = (const float*)d_in[7];
  const float* bhh1 = (const float*)d_in[8];
  const float* Wfc  = (const float*)d_in[9];
  const float* bfc  = (const float*)d_in[10];

  unsigned* runctr = (unsigned*)d_ws;
  unsigned* bslots = (unsigned*)((char*)d_ws + 256);
  float* h0s       = (float*)((char*)d_ws + 4096);
  float* h1s       = (float*)((char*)d_ws + 4096 + RD * H_DIM * sizeof(float));

  rnn2_merged<<<dim3(NWG), dim3(TPB), 0, stream>>>(
      xx, Wih0, Whh0, bih0, bhh0, Wih1, Whh1, bih1, bhh1, Wfc, bfc,
      (float*)d_out, runctr, bslots, h0s, h1s);
}

// Round 20
// 19071.117 us; speedup vs baseline: 1.3222x; 1.3222x over previous
//
#include <hip/hip_runtime.h>
#include <math.h>

#define L_SEQ 8192
#define I_DIM 256
#define H_DIM 2048
#define NWG0  64          // layer-0: 64 WGs x 32 rows (col-block: 4 rows/wave)
#define NWG1  128         // layer-1: 128 WGs x 16 rows (col-block: 2 rows/wave)
#define NWG   (NWG0 + NWG1)
#define TPB   512
#define RD    16          // h ring depth
#define RM    (RD - 1)
#define TLAG  11          // L0 throttle lag (checked every 4th step)

// ws (bytes): [0] runctr | [256..1024) bslots | [4096) h0 ring 16*2048 f32
//             | [4096+128K) h1 ring 16*2048 f32
//
// Base = round-17 (best: 18.9 ms): tagged dataflow (value = h + ctr(step),
// ctr = 4+8*((step>>4)&1), ring 16, |v-ctr|<=1 valid), per-run slot re-init,
// start barrier on monotone runctr, throttle lag 11 every 4th step, packed
// publishes, col-block compute (lane owns 32 cols, padded LDS pos j+(j>>3),
// 6-level shfl reduce, lane0 packed publish), L1 h0 prefetch (stale-read,
// vmcnt(1) wait), L0 x-trim. Excluded by experiment: r13 early h1 poll,
// r14 more L0 WGs, r16 cross-sync pf asm (crash), r18 wide-poll (fan-in не
// binding), r19 merged layers (coupling slack matters).
//
// Round-20 diff: HOT-POLL on data detects. poll4 (L0 h0 detect, L1 late h1
// detect, FC) and pf_finish's fallback lose s_sleep -- r18 proved contention
// is not binding, so the only effect is removing the 64-cy miss quantum and
// shortening post-landing detection. Throttle + start barrier keep backoff
// (genuinely long waits).

typedef float f32x4 __attribute__((ext_vector_type(4)));
typedef float f32x2 __attribute__((ext_vector_type(2)));

__device__ __forceinline__ void cstore1(float* p, float v) {
  asm volatile("global_store_dword %0, %1, off sc0 sc1" :: "v"(p), "v"(v) : "memory");
}
__device__ __forceinline__ void cstore2f(float* p, float a, float b) {
  f32x2 v; v.x = a; v.y = b;
  asm volatile("global_store_dwordx2 %0, %1, off sc0 sc1" :: "v"(p), "v"(v) : "memory");
}
__device__ __forceinline__ void cstore4f(float* p, float a, float b, float c, float d) {
  f32x4 v; v.x = a; v.y = b; v.z = c; v.w = d;
  asm volatile("global_store_dwordx4 %0, %1, off sc0 sc1" :: "v"(p), "v"(v) : "memory");
}
__device__ __forceinline__ void cstoreu(unsigned* p, unsigned v) {
  asm volatile("global_store_dword %0, %1, off sc0 sc1" :: "v"(p), "v"(v) : "memory");
}
__device__ __forceinline__ float cload1(const float* p) {
  float v;
  asm volatile("global_load_dword %0, %1, off sc0 sc1\n\ts_waitcnt vmcnt(0)"
               : "=v"(v) : "v"(p) : "memory");
  return v;
}
__device__ __forceinline__ unsigned cloadu(const unsigned* p) {
  unsigned v;
  asm volatile("global_load_dword %0, %1, off sc0 sc1\n\ts_waitcnt vmcnt(0)"
               : "=v"(v) : "v"(p) : "memory");
  return v;
}
__device__ __forceinline__ float4 cload4(const float* p) {
  float4 v;
  asm volatile("global_load_dwordx4 %0, %1, off sc0 sc1\n\ts_waitcnt vmcnt(0)"
               : "=v"(v) : "v"(p) : "memory");
  return v;
}
__device__ __forceinline__ float4 ld4(const float* p) {   // weight load, opaque
  float4 v;
  asm volatile("global_load_dwordx4 %0, %1, off\n\ts_waitcnt vmcnt(0)"
               : "=v"(v) : "v"(p) : "memory");
  return v;
}
// prefetch: issue WITHOUT waitcnt; drained by a later vmcnt
__device__ __forceinline__ void pf_issue(f32x4& v, const float* p) {
  asm volatile("global_load_dwordx4 %0, %1, off sc0 sc1" : "=&v"(v) : "v"(p) : "memory");
}
// wait: vmcnt(1) lets the recent publish store stay outstanding; the pf itself
// was drained by the previous iteration's poll4 vmcnt(0) (or prologue drain).
__device__ __forceinline__ void pf_wait1(f32x4& v) {
  asm volatile("s_waitcnt vmcnt(1)" : "+v"(v) :: "memory");
  __builtin_amdgcn_sched_barrier(0);
}
__device__ __forceinline__ float tagc(int step) {
  return 4.f + 8.f * (float)((step >> 4) & 1);
}
__device__ __forceinline__ bool ok4(float4 v, float c) {
  return __builtin_fabsf(v.x - c) <= 1.f && __builtin_fabsf(v.y - c) <= 1.f &&
         __builtin_fabsf(v.z - c) <= 1.f && __builtin_fabsf(v.w - c) <= 1.f;
}
__device__ __forceinline__ bool ok4x(f32x4 v, float c) {
  return __builtin_fabsf(v.x - c) <= 1.f && __builtin_fabsf(v.y - c) <= 1.f &&
         __builtin_fabsf(v.z - c) <= 1.f && __builtin_fabsf(v.w - c) <= 1.f;
}
// HOT data-detect: no sleep (data arrives within ~a us; contention non-binding per r18)
__device__ __forceinline__ float4 poll4(const float* p, float c) {
  float4 v = cload4(p);
  while (!ok4(v, c)) { v = cload4(p); }
  return make_float4(v.x - c, v.y - c, v.z - c, v.w - c);
}
// validate a prefetched granule; hot fallback if stale
__device__ __forceinline__ float4 pf_finish(f32x4 pf, const float* p, float c) {
  if (!ok4x(pf, c)) {
    do {
      float4 r = cload4(p);
      pf.x = r.x; pf.y = r.y; pf.z = r.z; pf.w = r.w;
    } while (!ok4x(pf, c));
  }
  return make_float4(pf.x - c, pf.y - c, pf.z - c, pf.w - c);
}
__device__ __forceinline__ float dot4(float4 a, float4 b) {
  return a.x * b.x + a.y * b.y + a.z * b.z + a.w * b.w;
}
__device__ __forceinline__ float tanh_fast(float v) {   // exact identity
  float e = __expf(2.f * v);
  return 1.f - 2.f / (e + 1.f);
}
__device__ __forceinline__ void start_barrier(unsigned* bslots, int wg, int tid, unsigned value) {
  __syncthreads();
  if (tid == 0) cstoreu(&bslots[wg], value);
  if (tid < NWG) {
    while ((int)(cloadu(&bslots[tid]) - value) < 0) __builtin_amdgcn_s_sleep(1);
  }
  __syncthreads();
}

__global__ __launch_bounds__(TPB, 2)
void rnn2_hotpoll(const float* __restrict__ x,
                  const float* __restrict__ Wih0, const float* __restrict__ Whh0,
                  const float* __restrict__ bih0, const float* __restrict__ bhh0,
                  const float* __restrict__ Wih1, const float* __restrict__ Whh1,
                  const float* __restrict__ bih1, const float* __restrict__ bhh1,
                  const float* __restrict__ Wfc,  const float* __restrict__ bfc,
                  float* __restrict__ out,
                  unsigned* __restrict__ runctr, unsigned* __restrict__ bslots,
                  float* __restrict__ h0s, float* __restrict__ h1s)
{
  const int wg   = blockIdx.x;
  const int tid  = threadIdx.x;
  const int lane = tid & 63;
  const int wv   = tid >> 6;
  __shared__ float4 lds4[2][1152];   // padded: [0..576) h0, [576..1152) h1

  const unsigned runbase = cloadu(runctr);

  if (wg < NWG0) {
    // ---- layer 0: wave wv owns rows r0..r0+3; lane owns cols [32l, 32l+32) ----
    const int r0 = wg * 32 + wv * 4;
    float4 whhr[32];   // [j*8+k]: row r0+j, col f4 k of the lane's 8
    float4 wihr[4];    // [j]: row r0+j, x cols [4l, 4l+4)
    {
      #pragma unroll
      for (int j = 0; j < 4; ++j) {
        const float* wr2 = Whh0 + (size_t)(r0 + j) * H_DIM + (lane << 5);
        #pragma unroll
        for (int k = 0; k < 8; ++k) whhr[j * 8 + k] = ld4(wr2 + (k << 2));
        wihr[j] = ld4(Wih0 + (size_t)(r0 + j) * I_DIM + (lane << 2));
      }
    }
    const float bs0 = bih0[r0] + bhh0[r0];
    const float bs1 = bih0[r0 + 1] + bhh0[r0 + 1];
    const float bs2 = bih0[r0 + 2] + bhh0[r0 + 2];
    const float bs3 = bih0[r0 + 3] + bhh0[r0 + 3];

    {   // re-init all 16 ring slots of owned rows: slot0 = tagged h0_0 (=4.0)
      int sl = tid >> 5; int r = wg * 32 + (tid & 31);
      cstore1(&h0s[sl * H_DIM + r], (sl == 0) ? 4.f : 0.f);
    }
    start_barrier(bslots, wg, tid, runbase + 1);

    // x-partials for s=1 (row 0 of x; lane's 4 cols)
    float xp0, xp1, xp2, xp3;
    {
      float4 xv = ((const float4*)x)[lane];
      xp0 = dot4(wihr[0], xv); xp1 = dot4(wihr[1], xv);
      xp2 = dot4(wihr[2], xv); xp3 = dot4(wihr[3], xv);
    }

    for (int s = 1; s <= L_SEQ; ++s) {
      const int P = s & 1;
      float4 hv = poll4(h0s + ((s - 1) & RM) * H_DIM + (tid << 2), tagc(s - 1));
      lds4[P][tid + (tid >> 3)] = hv;
      if ((s & 3) == 0 && s >= 12 && tid < NWG1) {
        // throttle (every 4th step, overlapped): all L1 WGs >= s-11
        const float tc = tagc(s - TLAG);
        const float* tp = h1s + ((s - TLAG) & RM) * H_DIM + (tid << 4);
        while (__builtin_fabsf(cload1(tp) - tc) > 1.f) __builtin_amdgcn_s_sleep(1);
      }
      __syncthreads();
      float p0 = xp0, p1 = xp1, p2 = xp2, p3 = xp3;
      #pragma unroll
      for (int k = 0; k < 8; ++k) {      // lane's 8 f4 of h0_{s-1}, padded layout
        float4 h = lds4[P][9 * lane + k];
        p0 += dot4(whhr[k], h);
        p1 += dot4(whhr[8 + k], h);
        p2 += dot4(whhr[16 + k], h);
        p3 += dot4(whhr[24 + k], h);
      }
      #pragma unroll
      for (int m = 1; m < 64; m <<= 1) { // 64-lane reduce, 4 parallel chains
        p0 += __shfl_xor(p0, m); p1 += __shfl_xor(p1, m);
        p2 += __shfl_xor(p2, m); p3 += __shfl_xor(p3, m);
      }
      if (lane == 0) {                   // lane0 holds all 4 rows: packed publish
        const float ct = tagc(s);
        cstore4f(h0s + (s & RM) * H_DIM + r0,
                 tanh_fast(p0 + bs0) + ct, tanh_fast(p1 + bs1) + ct,
                 tanh_fast(p2 + bs2) + ct, tanh_fast(p3 + bs3) + ct);
      }
      if (s < L_SEQ) {                   // x-partials for s+1, off the serial path
        float4 xv = ((const float4*)x)[s * 64 + lane];
        xp0 = dot4(wihr[0], xv); xp1 = dot4(wihr[1], xv);
        xp2 = dot4(wihr[2], xv); xp3 = dot4(wihr[3], xv);
      }
    }

    if (wg == 0) {
      // FC: sigmoid(h1_8192 . Wfc + bfc); slot 8192&15 = 0, ctr 4.
      // Last throttle (s=8192) gave L1 >= 8181 => slot 0 holds 8176 (tag 1,
      // rejected) or 8192 (tag 0, accepted); init value long overwritten.
      float4 hv = poll4(h1s + (tid << 2), tagc(L_SEQ));
      float4 wf = ((const float4*)Wfc)[tid];
      float pz = dot4(hv, wf);
      #pragma unroll
      for (int m = 1; m < 64; m <<= 1) pz += __shfl_xor(pz, m);
      float* red = (float*)&lds4[0][0];
      __syncthreads();
      if ((tid & 63) == 0) red[wv] = pz;
      __syncthreads();
      if (tid == 0) {
        float z = bfc[0];
        #pragma unroll
        for (int w = 0; w < 8; ++w) z += red[w];
        out[0] = 1.f / (1.f + __expf(-z));
        cstoreu(runctr, runbase + 1);
      }
    }
  } else {
    // ---- layer 1: wave wv owns rows r0, r0+1; lane owns cols [32l, 32l+32) ----
    const int wgl = wg - NWG0;
    const int r0  = wgl * 16 + wv * 2;
    float4 wihr[16], whhr[16];   // [j*8+k], j in {0,1}
    {
      #pragma unroll
      for (int j = 0; j < 2; ++j) {
        const float* wr = Wih1 + (size_t)(r0 + j) * H_DIM + (lane << 5);
        #pragma unroll
        for (int k = 0; k < 8; ++k) wihr[j * 8 + k] = ld4(wr + (k << 2));
        const float* wr2 = Whh1 + (size_t)(r0 + j) * H_DIM + (lane << 5);
        #pragma unroll
        for (int k = 0; k < 8; ++k) whhr[j * 8 + k] = ld4(wr2 + (k << 2));
      }
    }
    const float ba = bih1[r0] + bhh1[r0];
    const float bb = bih1[r0 + 1] + bhh1[r0 + 1];

    if (tid < 256) {   // re-init all 16 ring slots of owned rows
      int sl = tid >> 4; int r = wgl * 16 + (tid & 15);
      cstore1(&h1s[sl * H_DIM + r], (sl == 0) ? 4.f : 0.f);
    }
    start_barrier(bslots, wg, tid, runbase + 1);

    // prologue: issue prefetch of h0_1, then force a drain so pf is complete
    f32x4 pfA;
    pf_issue(pfA, h0s + (1 & RM) * H_DIM + (tid << 2));
    (void)cloadu(runctr);   // embedded vmcnt(0) drains pfA

    for (int t = 1; t <= L_SEQ; ++t) {
      const int P = t & 1;
      const float c0 = tagc(t);
      // phase A: h0_t from prefetch (validate; hot fallback)
      pf_wait1(pfA);
      float4 a = pf_finish(pfA, h0s + (t & RM) * H_DIM + (tid << 2), c0);
      lds4[P][tid + (tid >> 3)] = a;
      if (t < L_SEQ)   // next h0 prefetch; drained by this iter's h1 poll
        pf_issue(pfA, h0s + ((t + 1) & RM) * H_DIM + (tid << 2));
      __syncthreads();
      float pa = 0.f, pb = 0.f;
      #pragma unroll
      for (int k = 0; k < 8; ++k) {      // ih dot over lane's 8 f4 of h0_t
        float4 h = lds4[P][9 * lane + k];
        pa += dot4(wihr[k], h);
        pb += dot4(wihr[8 + k], h);
      }
      // phase B: h1_{t-1} -- the critical detect, polled late (proven position)
      float4 b = poll4(h1s + ((t - 1) & RM) * H_DIM + (tid << 2), tagc(t - 1));
      lds4[P][576 + tid + (tid >> 3)] = b;
      __syncthreads();
      #pragma unroll
      for (int k = 0; k < 8; ++k) {      // hh dot over lane's 8 f4 of h1_{t-1}
        float4 h = lds4[P][576 + 9 * lane + k];
        pa += dot4(whhr[k], h);
        pb += dot4(whhr[8 + k], h);
      }
      #pragma unroll
      for (int m = 1; m < 64; m <<= 1) { // 64-lane reduce, 2 parallel chains
        pa += __shfl_xor(pa, m); pb += __shfl_xor(pb, m);
      }
      if (lane == 0) {                   // lane0 holds both rows: packed publish
        const float ct = tagc(t);
        cstore2f(h1s + (t & RM) * H_DIM + r0,
                 tanh_fast(pa + ba) + ct, tanh_fast(pb + bb) + ct);
      }
    }
  }
}

extern "C" void kernel_launch(void* const* d_in, const int* in_sizes, int n_in,
                              void* d_out, int out_size, void* d_ws, size_t ws_size,
                              hipStream_t stream) {
  const float* xx   = (const float*)d_in[0];
  const float* Wih0 = (const float*)d_in[1];
  const float* Whh0 = (const float*)d_in[2];
  const float* bih0 = (const float*)d_in[3];
  const float* bhh0 = (const float*)d_in[4];
  const float* Wih1 = (const float*)d_in[5];
  const float* Whh1 = (const float*)d_in[6];
  const float* bih1 = (const float*)d_in[7];
  const float* bhh1 = (const float*)d_in[8];
  const float* Wfc  = (const float*)d_in[9];
  const float* bfc  = (const float*)d_in[10];

  unsigned* runctr = (unsigned*)d_ws;
  unsigned* bslots = (unsigned*)((char*)d_ws + 256);
  float* h0s       = (float*)((char*)d_ws + 4096);
  float* h1s       = (float*)((char*)d_ws + 4096 + RD * H_DIM * sizeof(float));

  rnn2_hotpoll<<<dim3(NWG), dim3(TPB), 0, stream>>>(
      xx, Wih0, Whh0, bih0, bhh0, Wih1, Whh1, bih1, bhh1, Wfc, bfc,
      (float*)d_out, runctr, bslots, h0s, h1s);
}

// Round 21
// 18934.286 us; speedup vs baseline: 1.3318x; 1.0072x over previous
//
#include <hip/hip_runtime.h>
#include <math.h>

#define L_SEQ 8192
#define I_DIM 256
#define H_DIM 2048
#define NWG0  64          // layer-0: 64 WGs x 32 rows (col-block: 4 rows/wave)
#define NWG1  128         // layer-1: 128 WGs x 16 rows (col-block: 2 rows/wave)
#define NWG   (NWG0 + NWG1)
#define TPB   512
#define RD    16          // h ring depth
#define RM    (RD - 1)
#define TLAG  11          // L0 throttle lag (checked every 4th step)

// ws (bytes): [0] runctr | [256..1024) bslots | [4096) h0 ring 16*2048 f32
//             | [4096+128K) h1 ring 16*2048 f32
//
// FINAL (= round-17, best measured: 18.9 ms, 2.31 us/step). Tagged dataflow:
// value = h + ctr(step), ctr = 4+8*((step>>4)&1), ring 16, |v-ctr|<=1 valid;
// per-run slot re-init (slot0 = tagged h_0 = 4.0, rest 0.0 invalid; 0xAA
// poison and 0.0 fail both tag windows); start barrier on monotone runctr;
// throttle lag 11 every 4th step; packed per-wave publishes; s_sleep backoff
// in data polls; col-block compute (lane owns 32 cols, padded LDS pos
// j+(j>>3), 6-level shfl reduce, lane0 packed publish); L1 h0 prefetch
// (stale-read, vmcnt(1) tie); L0 x-trim (x-partials off the serial path).
//
// Measured exclusions: r13 early h1 poll (-19%), r14 128 L0 WGs (-17%),
// r16 cross-sync conditional pf asm (crash), r18 wide-poll (-3.5%),
// r19 merged layers (-33%), r20 hot-poll (flat).
//
// Structural floor: each of the 8193 serial steps pays one cross-XCD
// publish->visibility->detect round trip through the coherence point
// (~1.5-1.7 us; per-XCD L2s non-coherent, weights span XCDs) + ~0.6 us
// compute wall. 8193 x 2.31 us = 18.9 ms.

typedef float f32x4 __attribute__((ext_vector_type(4)));
typedef float f32x2 __attribute__((ext_vector_type(2)));

__device__ __forceinline__ void cstore1(float* p, float v) {
  asm volatile("global_store_dword %0, %1, off sc0 sc1" :: "v"(p), "v"(v) : "memory");
}
__device__ __forceinline__ void cstore2f(float* p, float a, float b) {
  f32x2 v; v.x = a; v.y = b;
  asm volatile("global_store_dwordx2 %0, %1, off sc0 sc1" :: "v"(p), "v"(v) : "memory");
}
__device__ __forceinline__ void cstore4f(float* p, float a, float b, float c, float d) {
  f32x4 v; v.x = a; v.y = b; v.z = c; v.w = d;
  asm volatile("global_store_dwordx4 %0, %1, off sc0 sc1" :: "v"(p), "v"(v) : "memory");
}
__device__ __forceinline__ void cstoreu(unsigned* p, unsigned v) {
  asm volatile("global_store_dword %0, %1, off sc0 sc1" :: "v"(p), "v"(v) : "memory");
}
__device__ __forceinline__ float cload1(const float* p) {
  float v;
  asm volatile("global_load_dword %0, %1, off sc0 sc1\n\ts_waitcnt vmcnt(0)"
               : "=v"(v) : "v"(p) : "memory");
  return v;
}
__device__ __forceinline__ unsigned cloadu(const unsigned* p) {
  unsigned v;
  asm volatile("global_load_dword %0, %1, off sc0 sc1\n\ts_waitcnt vmcnt(0)"
               : "=v"(v) : "v"(p) : "memory");
  return v;
}
__device__ __forceinline__ float4 cload4(const float* p) {
  float4 v;
  asm volatile("global_load_dwordx4 %0, %1, off sc0 sc1\n\ts_waitcnt vmcnt(0)"
               : "=v"(v) : "v"(p) : "memory");
  return v;
}
__device__ __forceinline__ float4 ld4(const float* p) {   // weight load, opaque
  float4 v;
  asm volatile("global_load_dwordx4 %0, %1, off\n\ts_waitcnt vmcnt(0)"
               : "=v"(v) : "v"(p) : "memory");
  return v;
}
// prefetch: issue WITHOUT waitcnt; drained by a later vmcnt(0)
__device__ __forceinline__ void pf_issue(f32x4& v, const float* p) {
  asm volatile("global_load_dwordx4 %0, %1, off sc0 sc1" : "=&v"(v) : "v"(p) : "memory");
}
// wait: vmcnt(1) lets the recent publish store stay outstanding; the pf itself
// was drained by the previous iteration's poll4 vmcnt(0) (or prologue drain).
__device__ __forceinline__ void pf_wait1(f32x4& v) {
  asm volatile("s_waitcnt vmcnt(1)" : "+v"(v) :: "memory");
  __builtin_amdgcn_sched_barrier(0);
}
__device__ __forceinline__ float tagc(int step) {
  return 4.f + 8.f * (float)((step >> 4) & 1);
}
__device__ __forceinline__ bool ok4(float4 v, float c) {
  return __builtin_fabsf(v.x - c) <= 1.f && __builtin_fabsf(v.y - c) <= 1.f &&
         __builtin_fabsf(v.z - c) <= 1.f && __builtin_fabsf(v.w - c) <= 1.f;
}
__device__ __forceinline__ bool ok4x(f32x4 v, float c) {
  return __builtin_fabsf(v.x - c) <= 1.f && __builtin_fabsf(v.y - c) <= 1.f &&
         __builtin_fabsf(v.z - c) <= 1.f && __builtin_fabsf(v.w - c) <= 1.f;
}
__device__ __forceinline__ float4 poll4(const float* p, float c) {
  float4 v = cload4(p);
  while (!ok4(v, c)) { __builtin_amdgcn_s_sleep(1); v = cload4(p); }
  return make_float4(v.x - c, v.y - c, v.z - c, v.w - c);
}
// validate a prefetched granule; fall back to backoff-poll if stale
__device__ __forceinline__ float4 pf_finish(f32x4 pf, const float* p, float c) {
  if (!ok4x(pf, c)) {
    do {
      __builtin_amdgcn_s_sleep(1);
      float4 r = cload4(p);
      pf.x = r.x; pf.y = r.y; pf.z = r.z; pf.w = r.w;
    } while (!ok4x(pf, c));
  }
  return make_float4(pf.x - c, pf.y - c, pf.z - c, pf.w - c);
}
__device__ __forceinline__ float dot4(float4 a, float4 b) {
  return a.x * b.x + a.y * b.y + a.z * b.z + a.w * b.w;
}
__device__ __forceinline__ float tanh_fast(float v) {   // exact identity
  float e = __expf(2.f * v);
  return 1.f - 2.f / (e + 1.f);
}
__device__ __forceinline__ void start_barrier(unsigned* bslots, int wg, int tid, unsigned value) {
  __syncthreads();
  if (tid == 0) cstoreu(&bslots[wg], value);
  if (tid < NWG) {
    while ((int)(cloadu(&bslots[tid]) - value) < 0) __builtin_amdgcn_s_sleep(1);
  }
  __syncthreads();
}

__global__ __launch_bounds__(TPB, 2)
void rnn2_colb(const float* __restrict__ x,
               const float* __restrict__ Wih0, const float* __restrict__ Whh0,
               const float* __restrict__ bih0, const float* __restrict__ bhh0,
               const float* __restrict__ Wih1, const float* __restrict__ Whh1,
               const float* __restrict__ bih1, const float* __restrict__ bhh1,
               const float* __restrict__ Wfc,  const float* __restrict__ bfc,
               float* __restrict__ out,
               unsigned* __restrict__ runctr, unsigned* __restrict__ bslots,
               float* __restrict__ h0s, float* __restrict__ h1s)
{
  const int wg   = blockIdx.x;
  const int tid  = threadIdx.x;
  const int lane = tid & 63;
  const int wv   = tid >> 6;
  __shared__ float4 lds4[2][1152];   // padded: [0..576) h0, [576..1152) h1

  const unsigned runbase = cloadu(runctr);

  if (wg < NWG0) {
    // ---- layer 0: wave wv owns rows r0..r0+3; lane owns cols [32l, 32l+32) ----
    const int r0 = wg * 32 + wv * 4;
    float4 whhr[32];   // [j*8+k]: row r0+j, col f4 k of the lane's 8
    float4 wihr[4];    // [j]: row r0+j, x cols [4l, 4l+4)
    {
      #pragma unroll
      for (int j = 0; j < 4; ++j) {
        const float* wr2 = Whh0 + (size_t)(r0 + j) * H_DIM + (lane << 5);
        #pragma unroll
        for (int k = 0; k < 8; ++k) whhr[j * 8 + k] = ld4(wr2 + (k << 2));
        wihr[j] = ld4(Wih0 + (size_t)(r0 + j) * I_DIM + (lane << 2));
      }
    }
    const float bs0 = bih0[r0] + bhh0[r0];
    const float bs1 = bih0[r0 + 1] + bhh0[r0 + 1];
    const float bs2 = bih0[r0 + 2] + bhh0[r0 + 2];
    const float bs3 = bih0[r0 + 3] + bhh0[r0 + 3];

    {   // re-init all 16 ring slots of owned rows: slot0 = tagged h0_0 (=4.0)
      int sl = tid >> 5; int r = wg * 32 + (tid & 31);
      cstore1(&h0s[sl * H_DIM + r], (sl == 0) ? 4.f : 0.f);
    }
    start_barrier(bslots, wg, tid, runbase + 1);

    // x-partials for s=1 (row 0 of x; lane's 4 cols)
    float xp0, xp1, xp2, xp3;
    {
      float4 xv = ((const float4*)x)[lane];
      xp0 = dot4(wihr[0], xv); xp1 = dot4(wihr[1], xv);
      xp2 = dot4(wihr[2], xv); xp3 = dot4(wihr[3], xv);
    }

    for (int s = 1; s <= L_SEQ; ++s) {
      const int P = s & 1;
      float4 hv = poll4(h0s + ((s - 1) & RM) * H_DIM + (tid << 2), tagc(s - 1));
      lds4[P][tid + (tid >> 3)] = hv;
      if ((s & 3) == 0 && s >= 12 && tid < NWG1) {
        // throttle (every 4th step, overlapped): all L1 WGs >= s-11
        const float tc = tagc(s - TLAG);
        const float* tp = h1s + ((s - TLAG) & RM) * H_DIM + (tid << 4);
        while (__builtin_fabsf(cload1(tp) - tc) > 1.f) __builtin_amdgcn_s_sleep(1);
      }
      __syncthreads();
      float p0 = xp0, p1 = xp1, p2 = xp2, p3 = xp3;
      #pragma unroll
      for (int k = 0; k < 8; ++k) {      // lane's 8 f4 of h0_{s-1}, padded layout
        float4 h = lds4[P][9 * lane + k];
        p0 += dot4(whhr[k], h);
        p1 += dot4(whhr[8 + k], h);
        p2 += dot4(whhr[16 + k], h);
        p3 += dot4(whhr[24 + k], h);
      }
      #pragma unroll
      for (int m = 1; m < 64; m <<= 1) { // 64-lane reduce, 4 parallel chains
        p0 += __shfl_xor(p0, m); p1 += __shfl_xor(p1, m);
        p2 += __shfl_xor(p2, m); p3 += __shfl_xor(p3, m);
      }
      if (lane == 0) {                   // lane0 holds all 4 rows: packed publish
        const float ct = tagc(s);
        cstore4f(h0s + (s & RM) * H_DIM + r0,
                 tanh_fast(p0 + bs0) + ct, tanh_fast(p1 + bs1) + ct,
                 tanh_fast(p2 + bs2) + ct, tanh_fast(p3 + bs3) + ct);
      }
      if (s < L_SEQ) {                   // x-partials for s+1, off the serial path
        float4 xv = ((const float4*)x)[s * 64 + lane];
        xp0 = dot4(wihr[0], xv); xp1 = dot4(wihr[1], xv);
        xp2 = dot4(wihr[2], xv); xp3 = dot4(wihr[3], xv);
      }
    }

    if (wg == 0) {
      // FC: sigmoid(h1_8192 . Wfc + bfc); slot 8192&15 = 0, ctr 4.
      // Last throttle (s=8192) gave L1 >= 8181 => slot 0 holds 8176 (tag 1,
      // rejected) or 8192 (tag 0, accepted); init value long overwritten.
      float4 hv = poll4(h1s + (tid << 2), tagc(L_SEQ));
      float4 wf = ((const float4*)Wfc)[tid];
      float pz = dot4(hv, wf);
      #pragma unroll
      for (int m = 1; m < 64; m <<= 1) pz += __shfl_xor(pz, m);
      float* red = (float*)&lds4[0][0];
      __syncthreads();
      if ((tid & 63) == 0) red[wv] = pz;
      __syncthreads();
      if (tid == 0) {
        float z = bfc[0];
        #pragma unroll
        for (int w = 0; w < 8; ++w) z += red[w];
        out[0] = 1.f / (1.f + __expf(-z));
        cstoreu(runctr, runbase + 1);
      }
    }
  } else {
    // ---- layer 1: wave wv owns rows r0, r0+1; lane owns cols [32l, 32l+32) ----
    const int wgl = wg - NWG0;
    const int r0  = wgl * 16 + wv * 2;
    float4 wihr[16], whhr[16];   // [j*8+k], j in {0,1}
    {
      #pragma unroll
      for (int j = 0; j < 2; ++j) {
        const float* wr = Wih1 + (size_t)(r0 + j) * H_DIM + (lane << 5);
        #pragma unroll
        for (int k = 0; k < 8; ++k) wihr[j * 8 + k] = ld4(wr + (k << 2));
        const float* wr2 = Whh1 + (size_t)(r0 + j) * H_DIM + (lane << 5);
        #pragma unroll
        for (int k = 0; k < 8; ++k) whhr[j * 8 + k] = ld4(wr2 + (k << 2));
      }
    }
    const float ba = bih1[r0] + bhh1[r0];
    const float bb = bih1[r0 + 1] + bhh1[r0 + 1];

    if (tid < 256) {   // re-init all 16 ring slots of owned rows
      int sl = tid >> 4; int r = wgl * 16 + (tid & 15);
      cstore1(&h1s[sl * H_DIM + r], (sl == 0) ? 4.f : 0.f);
    }
    start_barrier(bslots, wg, tid, runbase + 1);

    // prologue: issue prefetch of h0_1, then force a drain so pf is complete
    f32x4 pfA;
    pf_issue(pfA, h0s + (1 & RM) * H_DIM + (tid << 2));
    (void)cloadu(runctr);   // embedded vmcnt(0) drains pfA

    for (int t = 1; t <= L_SEQ; ++t) {
      const int P = t & 1;
      const float c0 = tagc(t);
      // phase A: h0_t from prefetch (validate; poll fallback)
      pf_wait1(pfA);
      float4 a = pf_finish(pfA, h0s + (t & RM) * H_DIM + (tid << 2), c0);
      lds4[P][tid + (tid >> 3)] = a;
      if (t < L_SEQ)   // next h0 prefetch; drained by this iter's h1 poll
        pf_issue(pfA, h0s + ((t + 1) & RM) * H_DIM + (tid << 2));
      __syncthreads();
      float pa = 0.f, pb = 0.f;
      #pragma unroll
      for (int k = 0; k < 8; ++k) {      // ih dot over lane's 8 f4 of h0_t
        float4 h = lds4[P][9 * lane + k];
        pa += dot4(wihr[k], h);
        pb += dot4(wihr[8 + k], h);
      }
      // phase B: h1_{t-1} -- the critical detect, polled late (proven position)
      float4 b = poll4(h1s + ((t - 1) & RM) * H_DIM + (tid << 2), tagc(t - 1));
      lds4[P][576 + tid + (tid >> 3)] = b;
      __syncthreads();
      #pragma unroll
      for (int k = 0; k < 8; ++k) {      // hh dot over lane's 8 f4 of h1_{t-1}
        float4 h = lds4[P][576 + 9 * lane + k];
        pa += dot4(whhr[k], h);
        pb += dot4(whhr[8 + k], h);
      }
      #pragma unroll
      for (int m = 1; m < 64; m <<= 1) { // 64-lane reduce, 2 parallel chains
        pa += __shfl_xor(pa, m); pb += __shfl_xor(pb, m);
      }
      if (lane == 0) {                   // lane0 holds both rows: packed publish
        const float ct = tagc(t);
        cstore2f(h1s + (t & RM) * H_DIM + r0,
                 tanh_fast(pa + ba) + ct, tanh_fast(pb + bb) + ct);
      }
    }
  }
}

extern "C" void kernel_launch(void* const* d_in, const int* in_sizes, int n_in,
                              void* d_out, int out_size, void* d_ws, size_t ws_size,
                              hipStream_t stream) {
  const float* xx   = (const float*)d_in[0];
  const float* Wih0 = (const float*)d_in[1];
  const float* Whh0 = (const float*)d_in[2];
  const float* bih0 = (const float*)d_in[3];
  const float* bhh0 = (const float*)d_in[4];
  const float* Wih1 = (const float*)d_in[5];
  const float* Whh1 = (const float*)d_in[6];
  const float* bih1 = (const float*)d_in[7];
  const float* bhh1 = (const float*)d_in[8];
  const float* Wfc  = (const float*)d_in[9];
  const float* bfc  = (const float*)d_in[10];

  unsigned* runctr = (unsigned*)d_ws;
  unsigned* bslots = (unsigned*)((char*)d_ws + 256);
  float* h0s       = (float*)((char*)d_ws + 4096);
  float* h1s       = (float*)((char*)d_ws + 4096 + RD * H_DIM * sizeof(float));

  rnn2_colb<<<dim3(NWG), dim3(TPB), 0, stream>>>(
      xx, Wih0, Whh0, bih0, bhh0, Wih1, Whh1, bih1, bhh1, Wfc, bfc,
      (float*)d_out, runctr, bslots, h0s, h1s);
}